// Round 8
// baseline (378.496 us; speedup 1.0000x reference)
//
#include <hip/hip_runtime.h>
#include <math.h>

#define SEQ 2048
#define BATCH 4
#define DM 1024
#define DI 64

typedef __attribute__((ext_vector_type(8))) short bf16x8;
typedef __attribute__((ext_vector_type(4))) float f32x4;

__device__ __forceinline__ unsigned short f2bf(float f) {
  unsigned u = __float_as_uint(f);
  unsigned r = (u + 0x7fff + ((u >> 16) & 1)) >> 16;
  return (unsigned short)r;
}

__device__ __forceinline__ float bf2f(unsigned short u) {
  return __uint_as_float((unsigned)u << 16);
}

__device__ __forceinline__ void gload_lds16(const void* g, void* l) {
  __builtin_amdgcn_global_load_lds(
      (const __attribute__((address_space(1))) unsigned int*)g,
      (__attribute__((address_space(3))) unsigned int*)l, 16, 0, 0);
}

// ---------------------------------------------------------------------------
// Workspace layout (ushort unless noted):
//   WvT    : DM*DM        (Wv^T bf16)            2 MB
//   WqkT   : 2*DI*DM      (Wq^T, Wk^T bf16)      256 KB
//   qbf    : B*S*DI       (q proj bf16)          1 MB
//   kbf    : B*S*DI       (k proj bf16)          1 MB
//   vT     : B*DM*SEQ     (v proj^T bf16, invcol folded in) 16.75 MB
//   ebf    : B*S*S        (raw exp(s) bf16)      33.55 MB
//   vbf    : B*S*DM       (value cast bf16)      16.75 MB
//   colsum : B*S float    (sum_q e*invrs)        32 KB
//   invrs  : B*S float                           32 KB
//
// Math (no max-subtract; scores ~ N(0,1), exp <= ~250, fp32-safe):
//   e = exp(s)                  (scores -> ebf bf16; in-block rowsum -> invrs;
//                                in-block L2-hot re-read -> colsum atomics)
//   invcol = 1/(1e-9+colsum)    (computed on the fly by consumers; no kernel)
//   probs = e*invrs[q]*invcol[k] (probsout half of aten_probs launch)
//   out = invrs[q] * (ebf @ (vT*invcol))  (invcol folded into vproj epilogue)
//
// Launch order (5): trans(+zero) -> [qkproj | vcast] -> scores(+colsum) ->
//                   vproj -> [aten | probsout]
// ---------------------------------------------------------------------------

// ---------- merged transposes + colsum zero ---------------------------------
// y<16: Wv tile; y in {16,17}: Wq/Wk; y==18: zero colsum.
__global__ __launch_bounds__(256) void trans_kernel(
    const float* __restrict__ Wq, const float* __restrict__ Wk,
    const float* __restrict__ Wv,
    unsigned short* __restrict__ WqkT, unsigned short* __restrict__ WvT,
    float* __restrict__ colsum) {
  __shared__ unsigned short t[64][65];
  int lx = threadIdx.x & 63, ly = threadIdx.x >> 6;  // 64 x 4
  if (blockIdx.y < 16) {
    int bx = blockIdx.x * 64, by = blockIdx.y * 64;
#pragma unroll
    for (int i = 0; i < 64; i += 4)
      t[ly + i][lx] = f2bf(Wv[(size_t)(bx + ly + i) * DM + by + lx]);
    __syncthreads();
#pragma unroll
    for (int i = 0; i < 64; i += 4)
      WvT[(size_t)(by + ly + i) * DM + bx + lx] = t[lx][ly + i];
  } else if (blockIdx.y < 18) {
    int which = blockIdx.y - 16;
    const float* W = which ? Wk : Wq;
    unsigned short* WT = WqkT + (size_t)which * DI * DM;
    int bx = blockIdx.x * 64;
#pragma unroll
    for (int i = 0; i < 64; i += 4)
      t[ly + i][lx] = f2bf(W[(size_t)(bx + ly + i) * DI + lx]);
    __syncthreads();
#pragma unroll
    for (int i = 0; i < 64; i += 4)
      WT[(size_t)(ly + i) * DM + bx + lx] = t[lx][ly + i];
  } else {
    int idx = blockIdx.x * 256 + threadIdx.x;
    colsum[idx] = 0.f;
    colsum[idx + 4096] = 0.f;
  }
}

// ---------- merged: qkproj (blocks 0..511) | vcast (blocks 512..4607) -------
__global__ __launch_bounds__(256) void qkv_mix(
    const float* __restrict__ query, const float* __restrict__ key,
    const unsigned short* __restrict__ WqkT,
    const float* __restrict__ bq, const float* __restrict__ bk,
    unsigned short* __restrict__ qbf, unsigned short* __restrict__ kbf,
    const float* __restrict__ value, unsigned short* __restrict__ vbf) {
  __shared__ __align__(16) unsigned short As[32 * 32];   // 2 KB
  __shared__ __align__(16) unsigned short Bs[64 * 32];   // 4 KB
  int id = blockIdx.x;
  const int tid = threadIdx.x;
  if (id >= 512) {
    // ---- vcast: value fp32 -> bf16 ----
    size_t i = ((size_t)(id - 512) * 256 + tid) * 8;
    float4 a = *(const float4*)(value + i);
    float4 b = *(const float4*)(value + i + 4);
    bf16x8 h;
    h[0] = (short)f2bf(a.x); h[1] = (short)f2bf(a.y);
    h[2] = (short)f2bf(a.z); h[3] = (short)f2bf(a.w);
    h[4] = (short)f2bf(b.x); h[5] = (short)f2bf(b.y);
    h[6] = (short)f2bf(b.z); h[7] = (short)f2bf(b.w);
    *(bf16x8*)(vbf + i) = h;
    return;
  }
  // ---- qkproj: 32-row tiles ----
  int bx = id & 255, which = id >> 8;
  const float* A = (which ? key : query) + (size_t)bx * 32 * DM;
  const unsigned short* Bt = WqkT + (size_t)which * DI * DM;
  const float* bias = which ? bk : bq;
  unsigned short* outp = which ? kbf : qbf;

  const int lane = tid & 63, wave = tid >> 6;
  const int lrow = lane & 15, quad = lane >> 4;
  const int wr = (wave >> 1) * 16;                  // row group {0,16}
  const int wc = (wave & 1) * 32;                   // col group {0,32}
  const int sw = (quad ^ ((lrow >> 1) & 3)) * 8;    // swizzled chunk offset
  f32x4 acc[2] = {};

  const int am = tid >> 3, asub = tid & 7;
  const int akc = asub * 4;
  const int asl = am * 32 + (((asub >> 1) ^ ((am >> 1) & 3)) * 8) + (asub & 1) * 4;
  const int bn = tid >> 2;
  const int bkc = (((tid & 3) ^ ((bn >> 1) & 3)) * 8);

  for (int k0 = 0; k0 < DM; k0 += 32) {
    __syncthreads();
    gload_lds16(Bt + (size_t)bn * DM + k0 + bkc, Bs + wave * 512);
    float4 a = *(const float4*)(A + (size_t)am * DM + k0 + akc);
    ushort4 h;
    h.x = f2bf(a.x); h.y = f2bf(a.y); h.z = f2bf(a.z); h.w = f2bf(a.w);
    *(ushort4*)&As[asl] = h;
    __syncthreads();
    bf16x8 af = *(const bf16x8*)&As[(wr + lrow) * 32 + sw];
    bf16x8 b0 = *(const bf16x8*)&Bs[(wc + lrow) * 32 + sw];
    bf16x8 b1 = *(const bf16x8*)&Bs[(wc + 16 + lrow) * 32 + sw];
    acc[0] = __builtin_amdgcn_mfma_f32_16x16x32_bf16(af, b0, acc[0], 0, 0, 0);
    acc[1] = __builtin_amdgcn_mfma_f32_16x16x32_bf16(af, b1, acc[1], 0, 0, 0);
  }
  int sbase = bx * 8 + (wr >> 2) + quad;            // s index; b = reg
#pragma unroll
  for (int ni = 0; ni < 2; ++ni) {
    int n = wc + ni * 16 + lrow;
    float bb = bias[n];
#pragma unroll
    for (int reg = 0; reg < 4; ++reg)
      outp[((size_t)reg * SEQ + sbase) * DI + n] = f2bf(acc[ni][reg] + bb);
  }
}

// ---------------------------------------------------------------------------
// MFMA core, bb, 128x64 tile (vproj).
// ---------------------------------------------------------------------------
__device__ __forceinline__ void mfma_core_bb_12864(
    const unsigned short* __restrict__ At, int lda,
    const unsigned short* __restrict__ Bt, int ldb,
    int K, f32x4 (&acc)[4][2],
    unsigned short* As, unsigned short* Bs) {
  const int tid  = threadIdx.x;
  const int lane = tid & 63;
  const int wave = tid >> 6;
  const int wr   = (wave >> 1) * 64;
  const int wc   = (wave & 1) * 32;
  const int lrow = lane & 15;
  const int quad = lane >> 4;
  const int sw   = (quad ^ ((lrow >> 1) & 3)) * 8;
  const int bn   = tid >> 2;
  const int bkc  = ((tid & 3) ^ ((bn >> 1) & 3)) * 8;

  for (int k0 = 0; k0 < K; k0 += 32) {
    __syncthreads();
#pragma unroll
    for (int it = 0; it < 2; ++it) {
      int c = it * 256 + tid;
      int m = c >> 2, kc = ((c & 3) ^ ((m >> 1) & 3)) * 8;
      gload_lds16(At + (size_t)m * lda + k0 + kc,
                  As + (size_t)(it * 256 + wave * 64) * 8);
    }
    gload_lds16(Bt + (size_t)bn * ldb + k0 + bkc, Bs + wave * 512);
    __syncthreads();
    bf16x8 af[4], bfr[2];
#pragma unroll
    for (int mi = 0; mi < 4; ++mi)
      af[mi] = *(const bf16x8*)&As[(wr + mi * 16 + lrow) * 32 + sw];
#pragma unroll
    for (int ni = 0; ni < 2; ++ni)
      bfr[ni] = *(const bf16x8*)&Bs[(wc + ni * 16 + lrow) * 32 + sw];
#pragma unroll
    for (int mi = 0; mi < 4; ++mi)
#pragma unroll
      for (int ni = 0; ni < 2; ++ni)
        acc[mi][ni] = __builtin_amdgcn_mfma_f32_16x16x32_bf16(
            af[mi], bfr[ni], acc[mi][ni], 0, 0, 0);
  }
}

// ---------- V projection: vbf @ WvT -> vT bf16 (B,DM,S), invcol on the fly --
__global__ __launch_bounds__(256) void vproj_mfma(
    const unsigned short* __restrict__ vbf, const unsigned short* __restrict__ WvT,
    const float* __restrict__ bv, const float* __restrict__ colsum,
    unsigned short* __restrict__ vT) {
  __shared__ __align__(16) unsigned short As[128 * 32];      // 8 KB
  __shared__ __align__(16) unsigned short Bs[64 * 32];       // 4 KB
  __shared__ __align__(16) unsigned short ep[64 * 4 * 32];   // 16 KB [nn][b][ss]
  __shared__ float icl[128];                                 // [b][ss] invcol
  f32x4 acc[4][2] = {};
  int m0 = blockIdx.x * 128, n0 = blockIdx.y * 64;
  int s0 = m0 >> 2;
  if (threadIdx.x < 128)
    icl[threadIdx.x] =
        1.0f / (1e-9f + colsum[(size_t)(threadIdx.x >> 5) * SEQ + s0 + (threadIdx.x & 31)]);
  // (ordered before use by barriers inside mfma_core)
  mfma_core_bb_12864(vbf + (size_t)m0 * DM, DM, WvT + (size_t)n0 * DM, DM, DM,
                     acc, As, Bs);
  const int tid = threadIdx.x;
  const int lane = tid & 63, wave = tid >> 6;
  const int wr = (wave >> 1) * 64, wc = (wave & 1) * 32;
  const int lrow = lane & 15, quad = lane >> 4;
#pragma unroll
  for (int mi = 0; mi < 4; ++mi) {
    int ss = (wr >> 2) + mi * 4 + quad;           // 0..31; b = reg
#pragma unroll
    for (int ni = 0; ni < 2; ++ni) {
      int nn = wc + ni * 16 + lrow;               // 0..63
      float bias = bv[n0 + nn];
      int swz = (nn & 3) << 3;
#pragma unroll
      for (int reg = 0; reg < 4; ++reg)
        ep[nn * 128 + reg * 32 + (ss ^ swz)] =
            f2bf((acc[mi][ni][reg] + bias) * icl[reg * 32 + ss]);
    }
  }
  __syncthreads();
#pragma unroll
  for (int t8 = 0; t8 < 4; ++t8) {
    int c = t8 * 256 + tid;                       // 0..1023 chunks of 8
    int ss8 = (c & 3) * 8, b = (c >> 2) & 3, nn = c >> 4;
    uint4 vv = *(const uint4*)&ep[nn * 128 + b * 32 + (ss8 ^ ((nn & 3) << 3))];
    *(uint4*)&vT[((size_t)(b * DM + n0 + nn)) * SEQ + s0 + ss8] = vv;
  }
}

// ---------- scores row-panel + rowsum + colsum ------------------------------
// 16 q-rows x all k per block, 512 blocks. exp -> ebf bf16; in-block rowsum
// -> invrs (no atomics); second pass re-reads own L2-hot panel, accumulates
// invrs-weighted column sums -> colsum atomics.
__global__ __launch_bounds__(256) void scores_rowpanel(
    const unsigned short* __restrict__ qbf, const unsigned short* __restrict__ kbf,
    unsigned short* __restrict__ ebf, float* __restrict__ invrs,
    float* __restrict__ colsum) {
  __shared__ __align__(16) unsigned short Qs[16 * 64];    // 2 KB
  __shared__ __align__(16) unsigned short Ks[128 * 64];   // 16 KB
  __shared__ float red[4][16];
  __shared__ float irl[16];
  int bid = blockIdx.x;                  // 0..511
  int x = bid & 7, j = bid >> 3;
  int b = x >> 1;                        // batch (2 XCDs each)
  int q0 = (j * 2 + (x & 1)) * 16;       // q-tile base

  const int tid = threadIdx.x;
  const int lane = tid & 63, wave = tid >> 6;
  const int lrow = lane & 15, quad = lane >> 4;
  const int wc = wave * 32;
  const int sw = (quad ^ ((lrow >> 1) & 3)) * 8;
  const unsigned short* Q = qbf + ((size_t)b * SEQ + q0) * DI;
  const unsigned short* Kp = kbf + (size_t)b * SEQ * DI;
  unsigned short* C = ebf + (size_t)b * SEQ * SEQ;

  // Q staging: 16x64 = 128 chunks (waves 0-1 only; drained by in-loop barrier)
  if (tid < 128) {
    int m = tid >> 3, kk = (tid >> 2) & 1, jj = tid & 3;
    gload_lds16(Q + (size_t)m * DI + kk * 32 + ((jj ^ ((m >> 1) & 3)) * 8),
                Qs + (size_t)(tid & ~63) * 8);
  }

  float rsum[4] = {0.f, 0.f, 0.f, 0.f};
  for (int kt = 0; kt < 16; ++kt) {
    int k0 = kt * 128;
    __syncthreads();
#pragma unroll
    for (int it = 0; it < 4; ++it) {
      int c = it * 256 + tid;
      int n = c >> 3, kk = (c >> 2) & 1, jj = c & 3;
      gload_lds16(Kp + (size_t)(k0 + n) * DI + kk * 32 + ((jj ^ ((n >> 1) & 3)) * 8),
                  Ks + (size_t)(it * 256 + wave * 64) * 8);
    }
    __syncthreads();
    bf16x8 af[2], bfr[2][2];
#pragma unroll
    for (int kk = 0; kk < 2; ++kk) {
      af[kk] = *(const bf16x8*)&Qs[lrow * 64 + kk * 32 + sw];
#pragma unroll
      for (int ni = 0; ni < 2; ++ni)
        bfr[ni][kk] = *(const bf16x8*)&Ks[(wc + ni * 16 + lrow) * 64 + kk * 32 + sw];
    }
    f32x4 acc[2] = {};
#pragma unroll
    for (int ni = 0; ni < 2; ++ni) {
      acc[ni] = __builtin_amdgcn_mfma_f32_16x16x32_bf16(af[0], bfr[ni][0], acc[ni], 0, 0, 0);
      acc[ni] = __builtin_amdgcn_mfma_f32_16x16x32_bf16(af[1], bfr[ni][1], acc[ni], 0, 0, 0);
    }
#pragma unroll
    for (int ni = 0; ni < 2; ++ni) {
      int n = k0 + wc + ni * 16 + lrow;
#pragma unroll
      for (int reg = 0; reg < 4; ++reg) {
        float e = __expf(acc[ni][reg] * 0.125f);
        C[(size_t)(q0 + quad * 4 + reg) * SEQ + n] = f2bf(e);
        rsum[reg] += e;
      }
    }
  }
  // make this block's ebf writes visible to all its waves
  __threadfence_block();
  // reduce rsum over the 16-lane lrow group, then across waves
#pragma unroll
  for (int reg = 0; reg < 4; ++reg) {
    rsum[reg] += __shfl_xor(rsum[reg], 1);
    rsum[reg] += __shfl_xor(rsum[reg], 2);
    rsum[reg] += __shfl_xor(rsum[reg], 4);
    rsum[reg] += __shfl_xor(rsum[reg], 8);
  }
  if (lrow == 0) {
#pragma unroll
    for (int reg = 0; reg < 4; ++reg) red[wave][quad * 4 + reg] = rsum[reg];
  }
  __syncthreads();
  if (tid < 16) {
    float t = red[0][tid] + red[1][tid] + red[2][tid] + red[3][tid];
    float inv = 1.0f / t;
    invrs[(size_t)b * SEQ + q0 + tid] = inv;
    irl[tid] = inv;
  }
  __syncthreads();
  // second pass: column partials for this panel (reads are L2/L1-hot)
  int k8 = tid * 8;
  float cs[8] = {0.f, 0.f, 0.f, 0.f, 0.f, 0.f, 0.f, 0.f};
#pragma unroll 4
  for (int i = 0; i < 16; ++i) {
    const unsigned short* row = C + (size_t)(q0 + i) * SEQ + k8;
    ushort4 h0 = *(const ushort4*)(row);
    ushort4 h1 = *(const ushort4*)(row + 4);
    float ir = irl[i];
    cs[0] += bf2f(h0.x) * ir; cs[1] += bf2f(h0.y) * ir;
    cs[2] += bf2f(h0.z) * ir; cs[3] += bf2f(h0.w) * ir;
    cs[4] += bf2f(h1.x) * ir; cs[5] += bf2f(h1.y) * ir;
    cs[6] += bf2f(h1.z) * ir; cs[7] += bf2f(h1.w) * ir;
  }
#pragma unroll
  for (int jj = 0; jj < 8; ++jj)
    atomicAdd(&colsum[b * SEQ + k8 + jj], cs[jj]);
}

// ---------- merged: aten (blocks 0..511) | probsout (blocks 512..1535) ------
// aten: ebf(bf16) @ vT'(bf16) * invrs[q] -> out, BK=64, chunked XCD swizzle.
// probsout: probs = ebf * invrs[q] / (1e-9 + colsum[k]), fp32.
__global__ __launch_bounds__(256) void aten_probs(
    const unsigned short* __restrict__ ebf, const unsigned short* __restrict__ vT,
    const float* __restrict__ invrs, const float* __restrict__ colsum,
    float* __restrict__ out, float* __restrict__ probs) {
  __shared__ __align__(16) unsigned short As[128 * 64];   // 16 KB
  __shared__ __align__(16) unsigned short Bs[128 * 64];   // 16 KB
  __shared__ float irs[128];
  int id = blockIdx.x;
  const int tid = threadIdx.x;
  if (id >= 512) {
    // ---- probsout: 1024 blocks x 256 threads x 16 float4 ----
    size_t base = ((size_t)(id - 512) * 4096 + tid);
#pragma unroll 4
    for (int t = 0; t < 16; ++t) {
      size_t f = (base + (size_t)t * 256) * 4;
      int b = (int)(f >> 22);            // SEQ*SEQ = 2^22
      int q = (int)((f >> 11) & 2047);
      int k = (int)(f & 2047);
      ushort4 h = *(const ushort4*)(ebf + f);
      float ir = invrs[b * SEQ + q];
      float4 c = *(const float4*)(colsum + b * SEQ + k);
      float4 p;
      p.x = bf2f(h.x) * ir * (1.0f / (1e-9f + c.x));
      p.y = bf2f(h.y) * ir * (1.0f / (1e-9f + c.y));
      p.z = bf2f(h.z) * ir * (1.0f / (1e-9f + c.z));
      p.w = bf2f(h.w) * ir * (1.0f / (1e-9f + c.w));
      *(float4*)(probs + f) = p;
    }
    return;
  }
  // ---- aten ----
  int wg = (id & 7) * 64 + (id >> 3);          // bijective (512 % 8 == 0)
  int mb = wg & 15, nb = (wg >> 4) & 7, b = wg >> 7;
  int m0 = mb * 128, n0 = nb * 128;
  if (tid < 128)
    irs[tid] = invrs[(size_t)b * SEQ + m0 + tid];
  const unsigned short* At = ebf + ((size_t)b * SEQ + m0) * SEQ;
  const unsigned short* Bt = vT + ((size_t)b * DM + n0) * SEQ;

  const int lane = tid & 63, wave = tid >> 6;
  const int wr = (wave >> 1) * 64, wc = (wave & 1) * 64;
  const int lrow = lane & 15, quad = lane >> 4;
  const int sw = (quad ^ ((lrow >> 1) & 3)) * 8;

  f32x4 acc[4][4] = {};
  for (int k0 = 0; k0 < SEQ; k0 += 64) {
    __syncthreads();
#pragma unroll
    for (int it = 0; it < 4; ++it) {
      int c = it * 256 + tid;
      int m = c >> 3, kk = (c >> 2) & 1, jj = c & 3;
      gload_lds16(At + (size_t)m * SEQ + k0 + kk * 32 + ((jj ^ ((m >> 1) & 3)) * 8),
                  As + (size_t)(it * 256 + wave * 64) * 8);
    }
#pragma unroll
    for (int it = 0; it < 4; ++it) {
      int c = it * 256 + tid;
      int n = c >> 3, kk = (c >> 2) & 1, jj = c & 3;
      gload_lds16(Bt + (size_t)n * SEQ + k0 + kk * 32 + ((jj ^ ((n >> 1) & 3)) * 8),
                  Bs + (size_t)(it * 256 + wave * 64) * 8);
    }
    __syncthreads();
    bf16x8 bfr[4][2];
#pragma unroll
    for (int ni = 0; ni < 4; ++ni)
#pragma unroll
      for (int kk = 0; kk < 2; ++kk)
        bfr[ni][kk] = *(const bf16x8*)&Bs[(wc + ni * 16 + lrow) * 64 + kk * 32 + sw];
#pragma unroll
    for (int mi = 0; mi < 4; ++mi) {
      bf16x8 a0 = *(const bf16x8*)&As[(wr + mi * 16 + lrow) * 64 + sw];
      bf16x8 a1 = *(const bf16x8*)&As[(wr + mi * 16 + lrow) * 64 + 32 + sw];
#pragma unroll
      for (int ni = 0; ni < 4; ++ni) {
        acc[mi][ni] = __builtin_amdgcn_mfma_f32_16x16x32_bf16(a0, bfr[ni][0], acc[mi][ni], 0, 0, 0);
        acc[mi][ni] = __builtin_amdgcn_mfma_f32_16x16x32_bf16(a1, bfr[ni][1], acc[mi][ni], 0, 0, 0);
      }
    }
  }
#pragma unroll
  for (int mi = 0; mi < 4; ++mi) {
    int rb = wr + mi * 16 + quad * 4;
    int qr = m0 + rb;
#pragma unroll
    for (int ni = 0; ni < 4; ++ni) {
      int n = n0 + wc + ni * 16 + lrow;
#pragma unroll
      for (int reg = 0; reg < 4; ++reg)
        out[(size_t)(qr + reg) * (BATCH * DM) + b * DM + n] =
            acc[mi][ni][reg] * irs[rb + reg];
    }
  }
}

extern "C" void kernel_launch(void* const* d_in, const int* in_sizes, int n_in,
                              void* d_out, int out_size, void* d_ws, size_t ws_size,
                              hipStream_t stream) {
  const float* query = (const float*)d_in[0];
  const float* key   = (const float*)d_in[1];
  const float* value = (const float*)d_in[2];
  const float* Wq    = (const float*)d_in[3];
  const float* bq    = (const float*)d_in[4];
  const float* Wk    = (const float*)d_in[5];
  const float* bk    = (const float*)d_in[6];
  const float* Wv    = (const float*)d_in[7];
  const float* bv    = (const float*)d_in[8];

  float* out   = (float*)d_out;
  float* probs = out + (size_t)SEQ * BATCH * DM;        // BATCH*SEQ*SEQ floats

  unsigned short* WvT  = (unsigned short*)d_ws;
  unsigned short* WqkT = WvT  + (size_t)DM * DM;
  unsigned short* qbf  = WqkT + (size_t)2 * DI * DM;
  unsigned short* kbf  = qbf  + (size_t)BATCH * SEQ * DI;
  unsigned short* vT   = kbf  + (size_t)BATCH * SEQ * DI;
  unsigned short* ebf  = vT   + (size_t)BATCH * DM * SEQ;
  unsigned short* vbf  = ebf  + (size_t)BATCH * SEQ * SEQ;
  float* colsum = (float*)(vbf + (size_t)BATCH * SEQ * DM);
  float* invrs  = colsum + (size_t)BATCH * SEQ;

  trans_kernel<<<dim3(16, 19), 256, 0, stream>>>(Wq, Wk, Wv, WqkT, WvT, colsum);
  qkv_mix<<<dim3(512 + SEQ * BATCH * DM / 8 / 256), 256, 0, stream>>>(
      query, key, WqkT, bq, bk, qbf, kbf, value, vbf);
  scores_rowpanel<<<dim3(512), 256, 0, stream>>>(qbf, kbf, ebf, invrs, colsum);
  vproj_mfma<<<dim3(SEQ * BATCH / 128, DM / 64), 256, 0, stream>>>(
      vbf, WvT, bv, colsum, vT);
  aten_probs<<<dim3(512 + 1024), 256, 0, stream>>>(
      ebf, vT, invrs, colsum, out, probs);
}

// Round 10
// 316.781 us; speedup vs baseline: 1.1948x; 1.1948x over previous
//
#include <hip/hip_runtime.h>
#include <math.h>

#define SEQ 2048
#define BATCH 4
#define DM 1024
#define DI 64

typedef __attribute__((ext_vector_type(8))) short bf16x8;
typedef __attribute__((ext_vector_type(4))) float f32x4;

__device__ __forceinline__ unsigned short f2bf(float f) {
  unsigned u = __float_as_uint(f);
  unsigned r = (u + 0x7fff + ((u >> 16) & 1)) >> 16;
  return (unsigned short)r;
}

__device__ __forceinline__ float bf2f(unsigned short u) {
  return __uint_as_float((unsigned)u << 16);
}

__device__ __forceinline__ void gload_lds16(const void* g, void* l) {
  __builtin_amdgcn_global_load_lds(
      (const __attribute__((address_space(1))) unsigned int*)g,
      (__attribute__((address_space(3))) unsigned int*)l, 16, 0, 0);
}

// ---------------------------------------------------------------------------
// Workspace layout (ushort unless noted):
//   WvT    : DM*DM        (Wv^T bf16)            2 MB
//   WqkT   : 2*DI*DM      (Wq^T, Wk^T bf16)      256 KB
//   qbf    : B*S*DI       (q proj bf16)          1 MB
//   kbf    : B*S*DI       (k proj bf16)          1 MB
//   vT     : B*DM*SEQ     (v proj^T bf16, invcol folded in) 16.75 MB
//   ebf    : B*S*S        (raw exp(s) bf16)      33.55 MB
//   vbf    : B*S*DM       (value cast bf16)      16.75 MB
//   colsum : B*S float    (sum_q e*invrs)        32 KB
//   invrs  : B*S float                           32 KB
//
// Math (no max-subtract; scores ~ N(0,1), exp <= ~250, fp32-safe):
//   e = exp(s)                  (scores -> ebf bf16; in-block rowsum -> invrs)
//   colsum_k = sum_q e*invrs    (colsum kernel, bf16 weighted read)
//   invcol = 1/(1e-9+colsum)    (computed inline by consumers; no kernel)
//   probs = e*invrs[q]*invcol[k] (probsout)
//   out = invrs[q] * (ebf @ (vT*invcol))  (invcol folded into vproj epilogue)
//
// 64-ushort-row LDS swizzle (8-way, bank-conflict-free for ds_read_b128 at
// 128-B row stride): store chunk pos of row n sources logical chunk
// pos^(n&7); read logical chunk kk*4+quad at physical (kk*4+quad)^(lrow&7).
//
// Launch order (8): trans(+zero) -> qkproj -> vcast -> scores -> colsum ->
//                   vproj -> aten -> probsout
// ---------------------------------------------------------------------------

// ---------- merged transposes + colsum zero ---------------------------------
__global__ __launch_bounds__(256) void trans_kernel(
    const float* __restrict__ Wq, const float* __restrict__ Wk,
    const float* __restrict__ Wv,
    unsigned short* __restrict__ WqkT, unsigned short* __restrict__ WvT,
    float* __restrict__ colsum) {
  __shared__ unsigned short t[64][65];
  int lx = threadIdx.x & 63, ly = threadIdx.x >> 6;  // 64 x 4
  if (blockIdx.y < 16) {
    int bx = blockIdx.x * 64, by = blockIdx.y * 64;
#pragma unroll
    for (int i = 0; i < 64; i += 4)
      t[ly + i][lx] = f2bf(Wv[(size_t)(bx + ly + i) * DM + by + lx]);
    __syncthreads();
#pragma unroll
    for (int i = 0; i < 64; i += 4)
      WvT[(size_t)(by + ly + i) * DM + bx + lx] = t[lx][ly + i];
  } else if (blockIdx.y < 18) {
    int which = blockIdx.y - 16;
    const float* W = which ? Wk : Wq;
    unsigned short* WT = WqkT + (size_t)which * DI * DM;
    int bx = blockIdx.x * 64;
#pragma unroll
    for (int i = 0; i < 64; i += 4)
      t[ly + i][lx] = f2bf(W[(size_t)(bx + ly + i) * DI + lx]);
    __syncthreads();
#pragma unroll
    for (int i = 0; i < 64; i += 4)
      WT[(size_t)(ly + i) * DM + bx + lx] = t[lx][ly + i];
  } else {
    int idx = blockIdx.x * 256 + threadIdx.x;
    colsum[idx] = 0.f;
    colsum[idx + 4096] = 0.f;
  }
}

// ---------- Q/K projection via MFMA: 32-row tiles, 512 blocks ---------------
__global__ __launch_bounds__(256) void qkproj_mfma(
    const float* __restrict__ query, const float* __restrict__ key,
    const unsigned short* __restrict__ WqkT,
    const float* __restrict__ bq, const float* __restrict__ bk,
    unsigned short* __restrict__ qbf, unsigned short* __restrict__ kbf) {
  __shared__ __align__(16) unsigned short As[32 * 32];   // 2 KB
  __shared__ __align__(16) unsigned short Bs[64 * 32];   // 4 KB
  int which = blockIdx.y;
  const float* A = (which ? key : query) + (size_t)blockIdx.x * 32 * DM;
  const unsigned short* Bt = WqkT + (size_t)which * DI * DM;
  const float* bias = which ? bk : bq;
  unsigned short* outp = which ? kbf : qbf;

  const int tid = threadIdx.x;
  const int lane = tid & 63, wave = tid >> 6;
  const int lrow = lane & 15, quad = lane >> 4;
  const int wr = (wave >> 1) * 16;                  // row group {0,16}
  const int wc = (wave & 1) * 32;                   // col group {0,32}
  const int sw = (quad ^ ((lrow >> 1) & 3)) * 8;    // swizzled chunk offset
  f32x4 acc[2] = {};

  const int am = tid >> 3, asub = tid & 7;
  const int akc = asub * 4;
  const int asl = am * 32 + (((asub >> 1) ^ ((am >> 1) & 3)) * 8) + (asub & 1) * 4;
  const int bn = tid >> 2;
  const int bkc = (((tid & 3) ^ ((bn >> 1) & 3)) * 8);

  for (int k0 = 0; k0 < DM; k0 += 32) {
    __syncthreads();
    gload_lds16(Bt + (size_t)bn * DM + k0 + bkc, Bs + wave * 512);
    float4 a = *(const float4*)(A + (size_t)am * DM + k0 + akc);
    ushort4 h;
    h.x = f2bf(a.x); h.y = f2bf(a.y); h.z = f2bf(a.z); h.w = f2bf(a.w);
    *(ushort4*)&As[asl] = h;
    __syncthreads();
    bf16x8 af = *(const bf16x8*)&As[(wr + lrow) * 32 + sw];
    bf16x8 b0 = *(const bf16x8*)&Bs[(wc + lrow) * 32 + sw];
    bf16x8 b1 = *(const bf16x8*)&Bs[(wc + 16 + lrow) * 32 + sw];
    acc[0] = __builtin_amdgcn_mfma_f32_16x16x32_bf16(af, b0, acc[0], 0, 0, 0);
    acc[1] = __builtin_amdgcn_mfma_f32_16x16x32_bf16(af, b1, acc[1], 0, 0, 0);
  }
  int sbase = blockIdx.x * 8 + (wr >> 2) + quad;    // s index; b = reg
#pragma unroll
  for (int ni = 0; ni < 2; ++ni) {
    int n = wc + ni * 16 + lrow;
    float bb = bias[n];
#pragma unroll
    for (int reg = 0; reg < 4; ++reg)
      outp[((size_t)reg * SEQ + sbase) * DI + n] = f2bf(acc[ni][reg] + bb);
  }
}

// ---------- value fp32 -> bf16 cast -----------------------------------------
__global__ __launch_bounds__(256) void vcast_kernel(
    const float* __restrict__ value, unsigned short* __restrict__ vbf) {
  size_t i = ((size_t)blockIdx.x * 256 + threadIdx.x) * 8;
  float4 a = *(const float4*)(value + i);
  float4 b = *(const float4*)(value + i + 4);
  bf16x8 h;
  h[0] = (short)f2bf(a.x); h[1] = (short)f2bf(a.y);
  h[2] = (short)f2bf(a.z); h[3] = (short)f2bf(a.w);
  h[4] = (short)f2bf(b.x); h[5] = (short)f2bf(b.y);
  h[6] = (short)f2bf(b.z); h[7] = (short)f2bf(b.w);
  *(bf16x8*)(vbf + i) = h;
}

// ---------------------------------------------------------------------------
// MFMA core, bb, 128x64 tile (vproj). 32-ushort rows (proven conflict-free).
// ---------------------------------------------------------------------------
__device__ __forceinline__ void mfma_core_bb_12864(
    const unsigned short* __restrict__ At, int lda,
    const unsigned short* __restrict__ Bt, int ldb,
    int K, f32x4 (&acc)[4][2],
    unsigned short* As, unsigned short* Bs) {
  const int tid  = threadIdx.x;
  const int lane = tid & 63;
  const int wave = tid >> 6;
  const int wr   = (wave >> 1) * 64;
  const int wc   = (wave & 1) * 32;
  const int lrow = lane & 15;
  const int quad = lane >> 4;
  const int sw   = (quad ^ ((lrow >> 1) & 3)) * 8;
  const int bn   = tid >> 2;
  const int bkc  = ((tid & 3) ^ ((bn >> 1) & 3)) * 8;

  for (int k0 = 0; k0 < K; k0 += 32) {
    __syncthreads();
#pragma unroll
    for (int it = 0; it < 2; ++it) {
      int c = it * 256 + tid;
      int m = c >> 2, kc = ((c & 3) ^ ((m >> 1) & 3)) * 8;
      gload_lds16(At + (size_t)m * lda + k0 + kc,
                  As + (size_t)(it * 256 + wave * 64) * 8);
    }
    gload_lds16(Bt + (size_t)bn * ldb + k0 + bkc, Bs + wave * 512);
    __syncthreads();
    bf16x8 af[4], bfr[2];
#pragma unroll
    for (int mi = 0; mi < 4; ++mi)
      af[mi] = *(const bf16x8*)&As[(wr + mi * 16 + lrow) * 32 + sw];
#pragma unroll
    for (int ni = 0; ni < 2; ++ni)
      bfr[ni] = *(const bf16x8*)&Bs[(wc + ni * 16 + lrow) * 32 + sw];
#pragma unroll
    for (int mi = 0; mi < 4; ++mi)
#pragma unroll
      for (int ni = 0; ni < 2; ++ni)
        acc[mi][ni] = __builtin_amdgcn_mfma_f32_16x16x32_bf16(
            af[mi], bfr[ni], acc[mi][ni], 0, 0, 0);
  }
}

// ---------- V projection: vbf @ WvT -> vT bf16 (B,DM,S), invcol inline ------
__global__ __launch_bounds__(256) void vproj_mfma(
    const unsigned short* __restrict__ vbf, const unsigned short* __restrict__ WvT,
    const float* __restrict__ bv, const float* __restrict__ colsum,
    unsigned short* __restrict__ vT) {
  __shared__ __align__(16) unsigned short As[128 * 32];      // 8 KB
  __shared__ __align__(16) unsigned short Bs[64 * 32];       // 4 KB
  __shared__ __align__(16) unsigned short ep[64 * 4 * 32];   // 16 KB [nn][b][ss]
  __shared__ float icl[128];                                 // [b][ss] invcol
  f32x4 acc[4][2] = {};
  int m0 = blockIdx.x * 128, n0 = blockIdx.y * 64;
  int s0 = m0 >> 2;
  if (threadIdx.x < 128)
    icl[threadIdx.x] =
        1.0f / (1e-9f + colsum[(size_t)(threadIdx.x >> 5) * SEQ + s0 + (threadIdx.x & 31)]);
  // (ordered before use by barriers inside mfma_core)
  mfma_core_bb_12864(vbf + (size_t)m0 * DM, DM, WvT + (size_t)n0 * DM, DM, DM,
                     acc, As, Bs);
  const int tid = threadIdx.x;
  const int lane = tid & 63, wave = tid >> 6;
  const int wr = (wave >> 1) * 64, wc = (wave & 1) * 32;
  const int lrow = lane & 15, quad = lane >> 4;
#pragma unroll
  for (int mi = 0; mi < 4; ++mi) {
    int ss = (wr >> 2) + mi * 4 + quad;           // 0..31; b = reg
#pragma unroll
    for (int ni = 0; ni < 2; ++ni) {
      int nn = wc + ni * 16 + lrow;               // 0..63
      float bias = bv[n0 + nn];
      int swz = (nn & 3) << 3;
#pragma unroll
      for (int reg = 0; reg < 4; ++reg)
        ep[nn * 128 + reg * 32 + (ss ^ swz)] =
            f2bf((acc[mi][ni][reg] + bias) * icl[reg * 32 + ss]);
    }
  }
  __syncthreads();
#pragma unroll
  for (int t8 = 0; t8 < 4; ++t8) {
    int c = t8 * 256 + tid;                       // 0..1023 chunks of 8
    int ss8 = (c & 3) * 8, b = (c >> 2) & 3, nn = c >> 4;
    uint4 vv = *(const uint4*)&ep[nn * 128 + b * 32 + (ss8 ^ ((nn & 3) << 3))];
    *(uint4*)&vT[((size_t)(b * DM + n0 + nn)) * SEQ + s0 + ss8] = vv;
  }
}

// ---------- scores row-panel + rowsum: 16 q-rows x all k, 512 blocks --------
// exp -> ebf bf16; in-block rowsum -> invrs (no atomics). 8-way LDS swizzle.
__global__ __launch_bounds__(256) void scores_rowpanel(
    const unsigned short* __restrict__ qbf, const unsigned short* __restrict__ kbf,
    unsigned short* __restrict__ ebf, float* __restrict__ invrs) {
  __shared__ __align__(16) unsigned short Qs[16 * 64];    // 2 KB
  __shared__ __align__(16) unsigned short Ks[128 * 64];   // 16 KB
  __shared__ float red[4][16];
  int bid = blockIdx.x;                  // 0..511
  int x = bid & 7, j = bid >> 3;
  int b = x >> 1;                        // batch (2 XCDs each)
  int q0 = (j * 2 + (x & 1)) * 16;       // q-tile base

  const int tid = threadIdx.x;
  const int lane = tid & 63, wave = tid >> 6;
  const int lrow = lane & 15, quad = lane >> 4;
  const int wc = wave * 32;
  const int r7 = lrow & 7;
  const int c0 = (quad ^ r7) * 8;        // physical chunk for logical kk=0
  const int c1 = ((quad + 4) ^ r7) * 8;  // physical chunk for logical kk=1
  const unsigned short* Q = qbf + ((size_t)b * SEQ + q0) * DI;
  const unsigned short* Kp = kbf + (size_t)b * SEQ * DI;
  unsigned short* C = ebf + (size_t)b * SEQ * SEQ;

  // Q staging: 16 rows x 8 chunks (waves 0-1 only; drained by in-loop barrier)
  if (tid < 128) {
    int m = tid >> 3, pos = tid & 7;
    gload_lds16(Q + (size_t)m * DI + ((pos ^ (m & 7)) * 8),
                Qs + (size_t)(tid & ~63) * 8);
  }

  float rsum[4] = {0.f, 0.f, 0.f, 0.f};
  for (int kt = 0; kt < 16; ++kt) {
    int k0 = kt * 128;
    __syncthreads();
#pragma unroll
    for (int it = 0; it < 4; ++it) {
      int c = it * 256 + tid;
      int n = c >> 3, pos = c & 7;
      gload_lds16(Kp + (size_t)(k0 + n) * DI + ((pos ^ (n & 7)) * 8),
                  Ks + (size_t)(it * 256 + wave * 64) * 8);
    }
    __syncthreads();
    bf16x8 af[2], bfr[2][2];
    af[0] = *(const bf16x8*)&Qs[lrow * 64 + c0];
    af[1] = *(const bf16x8*)&Qs[lrow * 64 + c1];
#pragma unroll
    for (int ni = 0; ni < 2; ++ni) {
      int rr = (wc + ni * 16 + lrow) * 64;
      bfr[ni][0] = *(const bf16x8*)&Ks[rr + c0];
      bfr[ni][1] = *(const bf16x8*)&Ks[rr + c1];
    }
    f32x4 acc[2] = {};
#pragma unroll
    for (int ni = 0; ni < 2; ++ni) {
      acc[ni] = __builtin_amdgcn_mfma_f32_16x16x32_bf16(af[0], bfr[ni][0], acc[ni], 0, 0, 0);
      acc[ni] = __builtin_amdgcn_mfma_f32_16x16x32_bf16(af[1], bfr[ni][1], acc[ni], 0, 0, 0);
    }
#pragma unroll
    for (int ni = 0; ni < 2; ++ni) {
      int n = k0 + wc + ni * 16 + lrow;
#pragma unroll
      for (int reg = 0; reg < 4; ++reg) {
        float e = __expf(acc[ni][reg] * 0.125f);
        C[(size_t)(q0 + quad * 4 + reg) * SEQ + n] = f2bf(e);
        rsum[reg] += e;
      }
    }
  }
  // reduce rsum over the 16-lane lrow group, then across waves
#pragma unroll
  for (int reg = 0; reg < 4; ++reg) {
    rsum[reg] += __shfl_xor(rsum[reg], 1);
    rsum[reg] += __shfl_xor(rsum[reg], 2);
    rsum[reg] += __shfl_xor(rsum[reg], 4);
    rsum[reg] += __shfl_xor(rsum[reg], 8);
  }
  if (lrow == 0) {
#pragma unroll
    for (int reg = 0; reg < 4; ++reg) red[wave][quad * 4 + reg] = rsum[reg];
  }
  __syncthreads();
  if (tid < 16) {
    float t = red[0][tid] + red[1][tid] + red[2][tid] + red[3][tid];
    invrs[(size_t)b * SEQ + q0 + tid] = 1.0f / t;
  }
}

// ---------- column sums of row-normalized probs (bf16 weighted read) --------
__global__ __launch_bounds__(256) void colsum_kernel(
    const unsigned short* __restrict__ ebf, const float* __restrict__ invrs,
    float* __restrict__ colsum) {
  int b = blockIdx.z;
  int k = blockIdx.x * 256 + threadIdx.x;
  int q0 = blockIdx.y * 128;
  const unsigned short* p = ebf + (size_t)b * SEQ * SEQ + (size_t)q0 * SEQ + k;
  const float* ir = invrs + (size_t)b * SEQ + q0;
  float sum = 0.f;
#pragma unroll 4
  for (int i = 0; i < 128; ++i) sum += bf2f(p[(size_t)i * SEQ]) * ir[i];
  atomicAdd(&colsum[b * SEQ + k], sum);
}

// ---------- probs output: probs = ebf*invrs[q]/(1e-9+colsum[k]) fp32 --------
__global__ __launch_bounds__(256) void probsout_kernel(
    const unsigned short* __restrict__ ebf, const float* __restrict__ invrs,
    const float* __restrict__ colsum, float* __restrict__ probs) {
  size_t f = ((size_t)blockIdx.x * 256 + threadIdx.x) * 4;
  int b = (int)(f >> 22);            // SEQ*SEQ = 2^22
  int q = (int)((f >> 11) & 2047);
  int k = (int)(f & 2047);
  ushort4 h = *(const ushort4*)(ebf + f);
  float ir = invrs[b * SEQ + q];
  float4 c = *(const float4*)(colsum + b * SEQ + k);
  float4 p;
  p.x = bf2f(h.x) * ir * (1.0f / (1e-9f + c.x));
  p.y = bf2f(h.y) * ir * (1.0f / (1e-9f + c.y));
  p.z = bf2f(h.z) * ir * (1.0f / (1e-9f + c.z));
  p.w = bf2f(h.w) * ir * (1.0f / (1e-9f + c.w));
  *(float4*)(probs + f) = p;
}

// ---------- aten: ebf(bf16) @ vT'(bf16) * invrs[q] -> out (S,B,DM) ----------
// BK=64 with 8-way conflict-free swizzle; chunked XCD swizzle.
__global__ __launch_bounds__(256) void aten_mfma(
    const unsigned short* __restrict__ ebf, const unsigned short* __restrict__ vT,
    const float* __restrict__ invrs, float* __restrict__ out) {
  __shared__ __align__(16) unsigned short As[128 * 64];   // 16 KB
  __shared__ __align__(16) unsigned short Bs[128 * 64];   // 16 KB
  __shared__ float irs[128];
  int bid = blockIdx.x;                        // 0..511
  int wg = (bid & 7) * 64 + (bid >> 3);        // bijective (512 % 8 == 0)
  int mb = wg & 15, nb = (wg >> 4) & 7, b = wg >> 7;
  int m0 = mb * 128, n0 = nb * 128;
  if (threadIdx.x < 128)
    irs[threadIdx.x] = invrs[(size_t)b * SEQ + m0 + threadIdx.x];
  const unsigned short* At = ebf + ((size_t)b * SEQ + m0) * SEQ;
  const unsigned short* Bt = vT + ((size_t)b * DM + n0) * SEQ;

  const int tid = threadIdx.x;
  const int lane = tid & 63, wave = tid >> 6;
  const int wr = (wave >> 1) * 64, wc = (wave & 1) * 64;
  const int lrow = lane & 15, quad = lane >> 4;
  const int r7 = lrow & 7;
  const int c0 = (quad ^ r7) * 8;        // physical chunk for logical kk=0
  const int c1 = ((quad + 4) ^ r7) * 8;  // physical chunk for logical kk=1

  f32x4 acc[4][4] = {};
  for (int k0 = 0; k0 < SEQ; k0 += 64) {
    __syncthreads();
#pragma unroll
    for (int it = 0; it < 4; ++it) {
      int c = it * 256 + tid;
      int m = c >> 3, pos = c & 7;
      gload_lds16(At + (size_t)m * SEQ + k0 + ((pos ^ (m & 7)) * 8),
                  As + (size_t)(it * 256 + wave * 64) * 8);
    }
#pragma unroll
    for (int it = 0; it < 4; ++it) {
      int c = it * 256 + tid;
      int n = c >> 3, pos = c & 7;
      gload_lds16(Bt + (size_t)n * SEQ + k0 + ((pos ^ (n & 7)) * 8),
                  Bs + (size_t)(it * 256 + wave * 64) * 8);
    }
    __syncthreads();
    bf16x8 bfr[4][2];
#pragma unroll
    for (int ni = 0; ni < 4; ++ni) {
      int rr = (wc + ni * 16 + lrow) * 64;
      bfr[ni][0] = *(const bf16x8*)&Bs[rr + c0];
      bfr[ni][1] = *(const bf16x8*)&Bs[rr + c1];
    }
#pragma unroll
    for (int mi = 0; mi < 4; ++mi) {
      int rr = (wr + mi * 16 + lrow) * 64;
      bf16x8 a0 = *(const bf16x8*)&As[rr + c0];
      bf16x8 a1 = *(const bf16x8*)&As[rr + c1];
#pragma unroll
      for (int ni = 0; ni < 4; ++ni) {
        acc[mi][ni] = __builtin_amdgcn_mfma_f32_16x16x32_bf16(a0, bfr[ni][0], acc[mi][ni], 0, 0, 0);
        acc[mi][ni] = __builtin_amdgcn_mfma_f32_16x16x32_bf16(a1, bfr[ni][1], acc[mi][ni], 0, 0, 0);
      }
    }
  }
#pragma unroll
  for (int mi = 0; mi < 4; ++mi) {
    int rb = wr + mi * 16 + quad * 4;
    int qr = m0 + rb;
#pragma unroll
    for (int ni = 0; ni < 4; ++ni) {
      int n = n0 + wc + ni * 16 + lrow;
#pragma unroll
      for (int reg = 0; reg < 4; ++reg)
        out[(size_t)(qr + reg) * (BATCH * DM) + b * DM + n] =
            acc[mi][ni][reg] * irs[rb + reg];
    }
  }
}

extern "C" void kernel_launch(void* const* d_in, const int* in_sizes, int n_in,
                              void* d_out, int out_size, void* d_ws, size_t ws_size,
                              hipStream_t stream) {
  const float* query = (const float*)d_in[0];
  const float* key   = (const float*)d_in[1];
  const float* value = (const float*)d_in[2];
  const float* Wq    = (const float*)d_in[3];
  const float* bq    = (const float*)d_in[4];
  const float* Wk    = (const float*)d_in[5];
  const float* bk    = (const float*)d_in[6];
  const float* Wv    = (const float*)d_in[7];
  const float* bv    = (const float*)d_in[8];

  float* out   = (float*)d_out;
  float* probs = out + (size_t)SEQ * BATCH * DM;        // BATCH*SEQ*SEQ floats

  unsigned short* WvT  = (unsigned short*)d_ws;
  unsigned short* WqkT = WvT  + (size_t)DM * DM;
  unsigned short* qbf  = WqkT + (size_t)2 * DI * DM;
  unsigned short* kbf  = qbf  + (size_t)BATCH * SEQ * DI;
  unsigned short* vT   = kbf  + (size_t)BATCH * SEQ * DI;
  unsigned short* ebf  = vT   + (size_t)BATCH * DM * SEQ;
  unsigned short* vbf  = ebf  + (size_t)BATCH * SEQ * SEQ;
  float* colsum = (float*)(vbf + (size_t)BATCH * SEQ * DM);
  float* invrs  = colsum + (size_t)BATCH * SEQ;

  trans_kernel<<<dim3(16, 19), 256, 0, stream>>>(Wq, Wk, Wv, WqkT, WvT, colsum);
  qkproj_mfma<<<dim3(SEQ * BATCH / 32, 2), 256, 0, stream>>>(
      query, key, WqkT, bq, bk, qbf, kbf);
  vcast_kernel<<<(SEQ * BATCH * DM / 8) / 256, 256, 0, stream>>>(value, vbf);
  scores_rowpanel<<<dim3(512), 256, 0, stream>>>(qbf, kbf, ebf, invrs);
  colsum_kernel<<<dim3(SEQ / 256, SEQ / 128, BATCH), 256, 0, stream>>>(
      ebf, invrs, colsum);
  vproj_mfma<<<dim3(SEQ * BATCH / 128, DM / 64), 256, 0, stream>>>(
      vbf, WvT, bv, colsum, vT);
  aten_mfma<<<dim3(512), 256, 0, stream>>>(ebf, vT, invrs, out);
  probsout_kernel<<<(BATCH * SEQ * SEQ / 4) / 256, 256, 0, stream>>>(
      ebf, invrs, colsum, probs);
}